// Round 1
// baseline (370.363 us; speedup 1.0000x reference)
//
#include <hip/hip_runtime.h>

#define OUT 7
#define SRR 2
#define CCH 256

// Each block of 256 threads covers exactly one box m (C*49 = 12544 = 49 blocks
// of 256), so box loads broadcast and level branches are wave-uniform.
__global__ __launch_bounds__(256) void roi_pool_kernel(
    const float* __restrict__ f0, const float* __restrict__ f1,
    const float* __restrict__ f2, const float* __restrict__ f3,
    const float* __restrict__ boxes, float* __restrict__ out,
    int M, int R)
{
    int idx = blockIdx.x * blockDim.x + threadIdx.x;
    int total = M * CCH * OUT * OUT;
    if (idx >= total) return;

    int pw = idx % OUT;
    int ph = (idx / OUT) % OUT;
    int c  = (idx / (OUT * OUT)) % CCH;
    int m  = idx / (OUT * OUT * CCH);
    int n  = m / R;

    const float bx1 = boxes[m * 4 + 0];
    const float by1 = boxes[m * 4 + 1];
    const float bx2 = boxes[m * 4 + 2];
    const float by2 = boxes[m * 4 + 3];

    // assign_boxes_to_levels
    float sz  = sqrtf(fmaxf((bx2 - bx1) * (by2 - by1), 0.0f));
    int lvl = (int)floorf(4.0f + log2f(sz / 224.0f + 1e-8f));
    lvl = min(max(lvl, 2), 5) - 2;

    const float* feat;
    int H, W;
    float scale;
    switch (lvl) {
        case 0:  feat = f0; H = 256; W = 256; scale = 0.25f;    break;
        case 1:  feat = f1; H = 128; W = 128; scale = 0.125f;   break;
        case 2:  feat = f2; H = 64;  W = 64;  scale = 0.0625f;  break;
        default: feat = f3; H = 32;  W = 32;  scale = 0.03125f; break;
    }
    const float* fp = feat + (size_t)(n * CCH + c) * (size_t)(H * W);

    // aligned=True half-pixel offset
    float x1 = bx1 * scale - 0.5f;
    float y1 = by1 * scale - 0.5f;
    float x2 = bx2 * scale - 0.5f;
    float y2 = by2 * scale - 0.5f;
    float bw = (x2 - x1) * (1.0f / OUT);
    float bh = (y2 - y1) * (1.0f / OUT);

    float acc = 0.0f;
    #pragma unroll
    for (int iy = 0; iy < SRR; iy++) {
        float offy = (float)ph + ((float)iy + 0.5f) * 0.5f;
        float ys = y1 + offy * bh;
        bool vy = (ys >= -1.0f) && (ys <= (float)H);
        float y = fminf(fmaxf(ys, 0.0f), (float)(H - 1));
        int y0 = (int)y;               // y >= 0, trunc == floor
        int y1i = min(y0 + 1, H - 1);
        float ly = y - (float)y0;
        float hy = 1.0f - ly;
        #pragma unroll
        for (int ix = 0; ix < SRR; ix++) {
            float offx = (float)pw + ((float)ix + 0.5f) * 0.5f;
            float xs = x1 + offx * bw;
            bool vx = (xs >= -1.0f) && (xs <= (float)W);
            float x = fminf(fmaxf(xs, 0.0f), (float)(W - 1));
            int x0 = (int)x;
            int x1ii = min(x0 + 1, W - 1);
            float lx = x - (float)x0;
            float hx = 1.0f - lx;
            if (vy && vx) {
                float v00 = fp[y0 * W + x0];
                float v01 = fp[y0 * W + x1ii];
                float v10 = fp[y1i * W + x0];
                float v11 = fp[y1i * W + x1ii];
                acc += hy * hx * v00 + hy * lx * v01 + ly * hx * v10 + ly * lx * v11;
            }
        }
    }
    out[idx] = acc * 0.25f;
}

extern "C" void kernel_launch(void* const* d_in, const int* in_sizes, int n_in,
                              void* d_out, int out_size, void* d_ws, size_t ws_size,
                              hipStream_t stream) {
    const float* f0    = (const float*)d_in[0];
    const float* f1    = (const float*)d_in[1];
    const float* f2    = (const float*)d_in[2];
    const float* f3    = (const float*)d_in[3];
    const float* boxes = (const float*)d_in[4];
    float* out = (float*)d_out;

    int M = in_sizes[4] / 4;   // 1024
    int N = 2;
    int R = M / N;             // 512

    int total = M * CCH * OUT * OUT;
    int block = 256;
    int grid = (total + block - 1) / block;
    roi_pool_kernel<<<grid, block, 0, stream>>>(f0, f1, f2, f3, boxes, out, M, R);
}